// Round 4
// baseline (1387.080 us; speedup 1.0000x reference)
//
#include <hip/hip_runtime.h>

// Problem constants (Switch-Transformer tokens-choose router)
constexpr int Gn = 4;      // groups
constexpr int Tn = 4096;   // tokens per group
constexpr int Dn = 2048;   // d_model
constexpr int En = 64;     // experts
constexpr int Cn = 128;    // expert capacity
constexpr int NT = Gn * Tn;                  // 16384 tokens total
constexpr size_t NDC = (size_t)NT * En * Cn; // 134217728 elements per [g,t,e,c]

// ---------------------------------------------------------------------------
// Kernel 1: blocks 0..255  = fp64 router GEMM + softmax + top-2 + stats
//           blocks 256..1279 = zero-fill 1 MB each of the 1.07 GB output.
// Fill blocks co-reside with gemm blocks on each CU: their HBM writes overlap
// gemm's VALU/LDS work and hide its barrier stalls (gemm alone = 1 block/CU).
// GEMM block: 64 tokens x 64 experts, K-tiles of 64, per-lane 4x4 fp64 acc.
// LDS fp32 tiles (xs transposed [k][tok] pad 68, ws [k][e]) -> 2 B LDS/MAC.
// ---------------------------------------------------------------------------
__global__ __launch_bounds__(256) void k_gemmfill(
    const float* __restrict__ x, const float* __restrict__ Wm,
    const float* __restrict__ bias,
    double* __restrict__ gate, int* __restrict__ e1a, int* __restrict__ e2a,
    float* __restrict__ p1a, float* __restrict__ p2a,
    double* __restrict__ sumP, double* __restrict__ zsum,
    float4* __restrict__ outz)
{
    __shared__ double smem_d[4224];              // 33792 B, reused for stats

    if (blockIdx.x >= 256) {
        // ---- zero-fill path: 65536 float4 (1 MB) per block ----
        float4* dst = outz + (size_t)(blockIdx.x - 256) * 65536;
        const float4 z4 = make_float4(0.f, 0.f, 0.f, 0.f);
        #pragma unroll 8
        for (int u = 0; u < 256; ++u) dst[threadIdx.x + 256 * u] = z4;
        return;
    }

    float* xs = (float*)smem_d;                  // [64][68] fp32 (transposed)
    float* ws = (float*)smem_d + 64 * 68;        // [64][64] fp32

    const int tid  = threadIdx.x;
    const int lane = tid & 63;
    const int wave = tid >> 6;
    const int er   = lane & 15;      // expert quad: experts 4er..4er+3
    const int tr   = lane >> 4;      // token quad within wave
    const int tok0 = blockIdx.x * 64;
    const int g    = blockIdx.x >> 6;   // 64 blocks per group

    // staging mapping: kq = k-float4 within tile, tg = token group
    const int kq = tid & 15;
    const int tg = tid >> 4;

    double acc[4][4];
    #pragma unroll
    for (int i = 0; i < 4; ++i)
        #pragma unroll
        for (int j = 0; j < 4; ++j) acc[i][j] = 0.0;

    float4 px[4], pw[4];
    // prefetch tile 0
    #pragma unroll
    for (int j = 0; j < 4; ++j)
        px[j] = *(const float4*)(x + (size_t)(tok0 + tg * 4 + j) * Dn + 4 * kq);
    #pragma unroll
    for (int j = 0; j < 4; ++j)
        pw[j] = ((const float4*)Wm)[tid + 256 * j];

    const int tb = wave * 16 + tr * 4;   // token base for this lane
    const float* xsp = xs + tb;
    const float* wsp = ws + 4 * er;

    for (int it = 0; it < 32; ++it) {
        // commit prefetched regs to LDS (x transposed)
        #pragma unroll
        for (int j = 0; j < 4; ++j) {
            const float* pf = (const float*)&px[j];
            #pragma unroll
            for (int jj = 0; jj < 4; ++jj)
                xs[(4 * kq + jj) * 68 + tg * 4 + j] = pf[jj];
        }
        #pragma unroll
        for (int j = 0; j < 4; ++j)
            ((float4*)ws)[tid + 256 * j] = pw[j];
        __syncthreads();

        // prefetch next tile (completes during compute below)
        if (it < 31) {
            const int k0 = (it + 1) * 64;
            #pragma unroll
            for (int j = 0; j < 4; ++j)
                px[j] = *(const float4*)(x + (size_t)(tok0 + tg * 4 + j) * Dn + k0 + 4 * kq);
            #pragma unroll
            for (int j = 0; j < 4; ++j)
                pw[j] = ((const float4*)(Wm + (size_t)k0 * En))[tid + 256 * j];
        }

        // compute: 64 k-steps, 16 fp64 FMAs each
        #pragma unroll 4
        for (int k = 0; k < 64; ++k) {
            float4 xf = *(const float4*)(xsp + 68 * k);
            float4 wf = *(const float4*)(wsp + 64 * k);
            double xd0 = (double)xf.x, xd1 = (double)xf.y;
            double xd2 = (double)xf.z, xd3 = (double)xf.w;
            double wd0 = (double)wf.x, wd1 = (double)wf.y;
            double wd2 = (double)wf.z, wd3 = (double)wf.w;
            acc[0][0] += xd0 * wd0; acc[0][1] += xd0 * wd1;
            acc[0][2] += xd0 * wd2; acc[0][3] += xd0 * wd3;
            acc[1][0] += xd1 * wd0; acc[1][1] += xd1 * wd1;
            acc[1][2] += xd1 * wd2; acc[1][3] += xd1 * wd3;
            acc[2][0] += xd2 * wd0; acc[2][1] += xd2 * wd1;
            acc[2][2] += xd2 * wd2; acc[2][3] += xd2 * wd3;
            acc[3][0] += xd3 * wd0; acc[3][1] += xd3 * wd1;
            acc[3][2] += xd3 * wd2; acc[3][3] += xd3 * wd3;
        }
        __syncthreads();
    }

    // ---------------- epilogue: softmax + top-2 + stats ----------------
    const double b0 = (double)bias[4 * er + 0];
    const double b1 = (double)bias[4 * er + 1];
    const double b2 = (double)bias[4 * er + 2];
    const double b3 = (double)bias[4 * er + 3];
    double sp[4] = {0.0, 0.0, 0.0, 0.0};
    double zpart = 0.0;

    #pragma unroll
    for (int i = 0; i < 4; ++i) {
        double l0 = acc[i][0] + b0, l1 = acc[i][1] + b1;
        double l2 = acc[i][2] + b2, l3 = acc[i][3] + b3;
        double m = fmax(fmax(l0, l1), fmax(l2, l3));
        #pragma unroll
        for (int off = 8; off; off >>= 1) m = fmax(m, __shfl_xor(m, off));
        double e0v = exp(l0 - m), e1v = exp(l1 - m);
        double e2v = exp(l2 - m), e3v = exp(l3 - m);
        double s = e0v + e1v + e2v + e3v;
        #pragma unroll
        for (int off = 8; off; off >>= 1) s += __shfl_xor(s, off);
        double inv = 1.0 / s;
        double p0 = e0v * inv, p1 = e1v * inv, p2 = e2v * inv, p3 = e3v * inv;
        sp[0] += p0; sp[1] += p1; sp[2] += p2; sp[3] += p3;
        double lse = m + log(s);
        double z = (l0 - lse) * (l0 - lse) + (l1 - lse) * (l1 - lse)
                 + (l2 - lse) * (l2 - lse) + (l3 - lse) * (l3 - lse);
        #pragma unroll
        for (int off = 8; off; off >>= 1) z += __shfl_xor(z, off);
        zpart += z;

        // local top-2 over the 4 owned experts (ties -> lower index)
        double av, bv; int ai, bi;
        if (p1 > p0) { av = p1; ai = 4 * er + 1; bv = p0; bi = 4 * er; }
        else         { av = p0; ai = 4 * er;     bv = p1; bi = 4 * er + 1; }
        if (p2 > av)      { bv = av; bi = ai; av = p2; ai = 4 * er + 2; }
        else if (p2 > bv) { bv = p2; bi = 4 * er + 2; }
        if (p3 > av)      { bv = av; bi = ai; av = p3; ai = 4 * er + 3; }
        else if (p3 > bv) { bv = p3; bi = 4 * er + 3; }

        // butterfly merge across the 16 er-lanes
        #pragma unroll
        for (int off = 8; off; off >>= 1) {
            double av2 = __shfl_xor(av, off); int ai2 = __shfl_xor(ai, off);
            double bv2 = __shfl_xor(bv, off); int bi2 = __shfl_xor(bi, off);
            bool aWins = (av > av2) || (av == av2 && ai < ai2);
            if (aWins) {
                bool t = (bv > av2) || (bv == av2 && bi < ai2);
                if (!t) { bv = av2; bi = ai2; }
            } else {
                bool t = (av > bv2) || (av == bv2 && ai < bi2);
                if (t) { bv = av; bi = ai; }
                else   { bv = bv2; bi = bi2; }
                av = av2; ai = ai2;
            }
        }
        if (er == 0) {
            int tok = tok0 + tb + i;
            gate[tok] = av;
            e1a[tok] = ai;
            e2a[tok] = bi;
            p1a[tok] = (float)av;
            p2a[tok] = (float)bv;
        }
    }

    // block-level stats reduction (reuse smem, all waves past last barrier)
    double* sp_sm = smem_d;          // [16][64]
    double* z_sm  = smem_d + 16 * 64;
    const int r = wave * 4 + tr;
    #pragma unroll
    for (int j = 0; j < 4; ++j) sp_sm[r * 64 + 4 * er + j] = sp[j];
    if (er == 0) z_sm[r] = zpart;
    __syncthreads();
    if (wave == 0) {
        double v = 0.0;
        #pragma unroll
        for (int r2 = 0; r2 < 16; ++r2) v += sp_sm[r2 * 64 + lane];
        atomicAdd(&sumP[g * En + lane], v);
        if (lane == 0) {
            double zz = 0.0;
            #pragma unroll
            for (int r2 = 0; r2 < 16; ++r2) zz += z_sm[r2];
            atomicAdd(zsum, zz);
        }
    }
}

// ---------------------------------------------------------------------------
// Kernel 2: per-group bitonic sort of 4096 tokens by (gate desc, idx asc).
// ---------------------------------------------------------------------------
__global__ __launch_bounds__(1024) void k_sort(const double* __restrict__ gate,
                                               int* __restrict__ sidx)
{
    __shared__ double key[4096];
    __shared__ int    val[4096];
    const int g = blockIdx.x;
    for (int i = threadIdx.x; i < Tn; i += 1024) {
        key[i] = gate[g * Tn + i];
        val[i] = i;
    }
    __syncthreads();
    for (int k = 2; k <= Tn; k <<= 1) {
        for (int j = k >> 1; j > 0; j >>= 1) {
            for (int i = threadIdx.x; i < Tn; i += 1024) {
                int ixj = i ^ j;
                if (ixj > i) {
                    bool dir = ((i & k) == 0);
                    double ka = key[i], kb = key[ixj];
                    int    va = val[i], vb = val[ixj];
                    bool bFirst = (kb > ka) || (kb == ka && vb < va);
                    if (bFirst == dir) {
                        key[i] = kb; key[ixj] = ka;
                        val[i] = vb; val[ixj] = va;
                    }
                }
            }
            __syncthreads();
        }
    }
    for (int i = threadIdx.x; i < Tn; i += 1024) sidx[g * Tn + i] = val[i];
}

// ---------------------------------------------------------------------------
// Kernel 3: gather expert sequence in cumsum order (top-1 block then top-2).
// ---------------------------------------------------------------------------
__global__ void k_gather(const int* __restrict__ sidx,
                         const int* __restrict__ e1a, const int* __restrict__ e2a,
                         int* __restrict__ eseq, int* __restrict__ tseq)
{
    int idx = blockIdx.x * 256 + threadIdx.x;   // 0 .. 32767
    int g = idx >> 13;
    int j = idx & 8191;
    int s = (j < Tn) ? j : j - Tn;
    int tok = sidx[g * Tn + s];
    int e = (j < Tn) ? e1a[g * Tn + tok] : e2a[g * Tn + tok];
    eseq[idx] = e;
    tseq[idx] = tok;
}

// ---------------------------------------------------------------------------
// Kernel 4: sequential capacity assignment. One wave per group.
// ---------------------------------------------------------------------------
__global__ __launch_bounds__(64) void k_prio(
    const int* __restrict__ eseq, const int* __restrict__ tseq,
    int* __restrict__ pr1, int* __restrict__ pr2, int* __restrict__ cnt)
{
    const int g = blockIdx.x;
    const int lane = threadIdx.x;
    int base = 0;   // running count for expert == lane

    for (int c = 0; c < 2 * Tn / 64; ++c) {
        int j   = c * 64 + lane;
        int e   = eseq[g * 2 * Tn + j];
        int tok = tseq[g * 2 * Tn + j];

        unsigned long long m  = ~0ull;
        unsigned long long mo = ~0ull;
        #pragma unroll
        for (int bb = 0; bb < 6; ++bb) {
            unsigned long long bal = __ballot((e >> bb) & 1);
            m  &= ((e    >> bb) & 1) ? bal : ~bal;
            mo &= ((lane >> bb) & 1) ? bal : ~bal;
        }
        int rank   = __popcll(m & ((1ull << lane) - 1ull));
        int myBase = __shfl(base, e);
        int pr     = myBase + rank;
        if (j < Tn) pr1[g * Tn + tok] = pr;
        else        pr2[g * Tn + tok] = pr;
        base += __popcll(mo);
    }
    cnt[g * En + lane] = base;
}

// ---------------------------------------------------------------------------
// Kernel 5: blocks 0..63 scatter the <=2 nonzeros per token into
// dispatch & combine; block 64 finalizes aux_loss and z_loss.
// ---------------------------------------------------------------------------
__global__ __launch_bounds__(256) void k_scatfin(
    const int* __restrict__ e1a, const int* __restrict__ e2a,
    const float* __restrict__ p1a, const float* __restrict__ p2a,
    const int* __restrict__ pr1, const int* __restrict__ pr2,
    const int* __restrict__ cnt, const double* __restrict__ sumP,
    const double* __restrict__ zsum, float* __restrict__ out)
{
    if (blockIdx.x == 64) {
        __shared__ double red[256];
        int t = threadIdx.x;
        red[t] = (double)cnt[t] * sumP[t];
        __syncthreads();
        for (int s = 128; s; s >>= 1) {
            if (t < s) red[t] += red[t + s];
            __syncthreads();
        }
        if (t == 0) {
            double aux = red[0] * ((double)En / ((double)Gn * (double)Tn * (double)Tn));
            out[2 * NDC]     = (float)aux;
            out[2 * NDC + 1] = (float)(zsum[0] / ((double)Gn * Tn * En));
        }
        return;
    }

    int tok = blockIdx.x * 256 + threadIdx.x;
    size_t base = (size_t)tok * En * Cn;
    int p = pr1[tok];
    if (p < Cn) {
        size_t o = base + (size_t)e1a[tok] * Cn + p;
        out[o] = 1.0f;
        out[NDC + o] = p1a[tok];
    }
    p = pr2[tok];
    if (p < Cn) {
        size_t o = base + (size_t)e2a[tok] * Cn + p;
        out[o] = 1.0f;
        out[NDC + o] = p2a[tok];
    }
}

// ---------------------------------------------------------------------------
extern "C" void kernel_launch(void* const* d_in, const int* in_sizes, int n_in,
                              void* d_out, int out_size, void* d_ws, size_t ws_size,
                              hipStream_t stream)
{
    const float* x    = (const float*)d_in[0];   // [G,T,D] fp32
    const float* Wm   = (const float*)d_in[1];   // [D,E] fp32
    const float* bias = (const float*)d_in[2];   // [E] fp32
    float* out = (float*)d_out;

    // workspace carve (8-byte aligned in declaration order)
    double* gate = (double*)d_ws;            // NT doubles
    double* sumP = gate + NT;                // G*E doubles
    double* zsum = sumP + Gn * En;           // 1 double
    int* e1a  = (int*)(zsum + 1);            // NT
    int* e2a  = e1a + NT;                    // NT
    int* sidx = e2a + NT;                    // NT
    int* pr1  = sidx + NT;                   // NT
    int* pr2  = pr1 + NT;                    // NT
    int* cnt  = pr2 + NT;                    // G*E
    int* eseq = cnt + Gn * En;               // G*2T
    int* tseq = eseq + Gn * 2 * Tn;          // G*2T
    float* p1a = (float*)(tseq + Gn * 2 * Tn);
    float* p2a = p1a + NT;

    // zero the fp64 accumulators (sumP[256] + zsum[1], contiguous)
    hipMemsetAsync(sumP, 0, (Gn * En + 1) * sizeof(double), stream);

    // GEMM (256 blocks) + zero-fill of the 1.07 GB output (1024 blocks),
    // co-resident on every CU so fill writes overlap gemm compute.
    k_gemmfill<<<1280, 256, 0, stream>>>(x, Wm, bias, gate, e1a, e2a, p1a, p2a,
                                         sumP, zsum, (float4*)out);

    k_sort<<<Gn, 1024, 0, stream>>>(gate, sidx);
    k_gather<<<(Gn * 2 * Tn) / 256, 256, 0, stream>>>(sidx, e1a, e2a, eseq, tseq);
    k_prio<<<Gn, 64, 0, stream>>>(eseq, tseq, pr1, pr2, cnt);
    k_scatfin<<<65, 256, 0, stream>>>(e1a, e2a, p1a, p2a, pr1, pr2,
                                      cnt, sumP, zsum, out);
}

// Round 5
// 1381.842 us; speedup vs baseline: 1.0038x; 1.0038x over previous
//
#include <hip/hip_runtime.h>

// Problem constants (Switch-Transformer tokens-choose router)
constexpr int Gn = 4;      // groups
constexpr int Tn = 4096;   // tokens per group
constexpr int Dn = 2048;   // d_model
constexpr int En = 64;     // experts
constexpr int Cn = 128;    // expert capacity
constexpr int NT = Gn * Tn;                  // 16384 tokens total
constexpr size_t NDC = (size_t)NT * En * Cn; // 134217728 elements per [g,t,e,c]

// ---------------------------------------------------------------------------
// Kernel 1: blocks 0..255   = fp64 router GEMM + softmax + top-2 + stats
//           blocks 256..1023 = zero-fill 1 MB each (768 MB of the output).
// GEMM block: 64 tokens x 64 experts, K-tiles of 64, per-lane 4x4 fp64 acc.
// LDS fp32 tiles, BOTH row-major along k: xs[64 tok][68], ws[64 k][64 e].
// All staging writes and compute reads are ds_*_b128; inner loop processes
// 4 k per step (8 b128 reads + 64 fp64 FMAs).
// ---------------------------------------------------------------------------
__global__ __launch_bounds__(256) void k_gemmfill(
    const float* __restrict__ x, const float* __restrict__ Wm,
    const float* __restrict__ bias,
    double* __restrict__ gate, int* __restrict__ e1a, int* __restrict__ e2a,
    float* __restrict__ p1a, float* __restrict__ p2a,
    double* __restrict__ sumP, double* __restrict__ zsum,
    float4* __restrict__ outz)
{
    __shared__ double smem_d[4224];              // 33792 B, reused for stats

    if (blockIdx.x >= 256) {
        // ---- zero-fill path: 65536 float4 (1 MB) per block ----
        float4* dst = outz + (size_t)(blockIdx.x - 256) * 65536;
        const float4 z4 = make_float4(0.f, 0.f, 0.f, 0.f);
        #pragma unroll 8
        for (int u = 0; u < 256; ++u) dst[threadIdx.x + 256 * u] = z4;
        return;
    }

    float* xs = (float*)smem_d;                  // [64][68] fp32, row = token
    float* ws = (float*)smem_d + 64 * 68;        // [64][64] fp32, row = k

    const int tid  = threadIdx.x;
    const int lane = tid & 63;
    const int wave = tid >> 6;
    const int er   = lane & 15;      // expert quad: experts 4er..4er+3
    const int tr   = lane >> 4;      // token quad within wave
    const int tok0 = blockIdx.x * 64;
    const int g    = blockIdx.x >> 6;   // 64 blocks per group

    // staging mapping: kq = k-float4 within tile, tg = token group
    const int kq = tid & 15;
    const int tg = tid >> 4;

    double acc[4][4];
    #pragma unroll
    for (int i = 0; i < 4; ++i)
        #pragma unroll
        for (int j = 0; j < 4; ++j) acc[i][j] = 0.0;

    float4 px[4], pw[4];
    // prefetch tile 0
    #pragma unroll
    for (int j = 0; j < 4; ++j)
        px[j] = *(const float4*)(x + (size_t)(tok0 + tg * 4 + j) * Dn + 4 * kq);
    #pragma unroll
    for (int j = 0; j < 4; ++j)
        pw[j] = ((const float4*)Wm)[tid + 256 * j];

    const int tb = wave * 16 + tr * 4;   // token base for this lane
    const float* xsp = xs + tb * 68;
    const float* wsp = ws + 4 * er;

    for (int it = 0; it < 32; ++it) {
        // commit prefetched regs to LDS — all b128 writes
        #pragma unroll
        for (int j = 0; j < 4; ++j)
            *(float4*)(xs + (tg * 4 + j) * 68 + 4 * kq) = px[j];
        #pragma unroll
        for (int j = 0; j < 4; ++j)
            ((float4*)ws)[tid + 256 * j] = pw[j];
        __syncthreads();

        // prefetch next tile (completes during compute below)
        if (it < 31) {
            const int k0 = (it + 1) * 64;
            #pragma unroll
            for (int j = 0; j < 4; ++j)
                px[j] = *(const float4*)(x + (size_t)(tok0 + tg * 4 + j) * Dn + k0 + 4 * kq);
            #pragma unroll
            for (int j = 0; j < 4; ++j)
                pw[j] = ((const float4*)(Wm + (size_t)k0 * En))[tid + 256 * j];
        }

        // compute: 16 k4-steps; each = 8 b128 reads + 64 fp64 FMAs
        #pragma unroll 2
        for (int kk = 0; kk < 16; ++kk) {
            float4 xq0 = *(const float4*)(xsp + 0 * 68 + 4 * kk);
            float4 xq1 = *(const float4*)(xsp + 1 * 68 + 4 * kk);
            float4 xq2 = *(const float4*)(xsp + 2 * 68 + 4 * kk);
            float4 xq3 = *(const float4*)(xsp + 3 * 68 + 4 * kk);
            #pragma unroll
            for (int j = 0; j < 4; ++j) {
                float4 wf = *(const float4*)(wsp + (4 * kk + j) * 64);
                double w0 = (double)wf.x, w1 = (double)wf.y;
                double w2 = (double)wf.z, w3 = (double)wf.w;
                double xv0 = (double)((const float*)&xq0)[j];
                double xv1 = (double)((const float*)&xq1)[j];
                double xv2 = (double)((const float*)&xq2)[j];
                double xv3 = (double)((const float*)&xq3)[j];
                acc[0][0] += xv0 * w0; acc[0][1] += xv0 * w1;
                acc[0][2] += xv0 * w2; acc[0][3] += xv0 * w3;
                acc[1][0] += xv1 * w0; acc[1][1] += xv1 * w1;
                acc[1][2] += xv1 * w2; acc[1][3] += xv1 * w3;
                acc[2][0] += xv2 * w0; acc[2][1] += xv2 * w1;
                acc[2][2] += xv2 * w2; acc[2][3] += xv2 * w3;
                acc[3][0] += xv3 * w0; acc[3][1] += xv3 * w1;
                acc[3][2] += xv3 * w2; acc[3][3] += xv3 * w3;
            }
        }
        __syncthreads();
    }

    // ---------------- epilogue: softmax + top-2 + stats ----------------
    const double b0 = (double)bias[4 * er + 0];
    const double b1 = (double)bias[4 * er + 1];
    const double b2 = (double)bias[4 * er + 2];
    const double b3 = (double)bias[4 * er + 3];
    double sp[4] = {0.0, 0.0, 0.0, 0.0};
    double zpart = 0.0;

    #pragma unroll
    for (int i = 0; i < 4; ++i) {
        double l0 = acc[i][0] + b0, l1 = acc[i][1] + b1;
        double l2 = acc[i][2] + b2, l3 = acc[i][3] + b3;
        double m = fmax(fmax(l0, l1), fmax(l2, l3));
        #pragma unroll
        for (int off = 8; off; off >>= 1) m = fmax(m, __shfl_xor(m, off));
        double e0v = exp(l0 - m), e1v = exp(l1 - m);
        double e2v = exp(l2 - m), e3v = exp(l3 - m);
        double s = e0v + e1v + e2v + e3v;
        #pragma unroll
        for (int off = 8; off; off >>= 1) s += __shfl_xor(s, off);
        double inv = 1.0 / s;
        double p0 = e0v * inv, p1 = e1v * inv, p2 = e2v * inv, p3 = e3v * inv;
        sp[0] += p0; sp[1] += p1; sp[2] += p2; sp[3] += p3;
        double lse = m + log(s);
        double z = (l0 - lse) * (l0 - lse) + (l1 - lse) * (l1 - lse)
                 + (l2 - lse) * (l2 - lse) + (l3 - lse) * (l3 - lse);
        #pragma unroll
        for (int off = 8; off; off >>= 1) z += __shfl_xor(z, off);
        zpart += z;

        // local top-2 over the 4 owned experts (ties -> lower index)
        double av, bv; int ai, bi;
        if (p1 > p0) { av = p1; ai = 4 * er + 1; bv = p0; bi = 4 * er; }
        else         { av = p0; ai = 4 * er;     bv = p1; bi = 4 * er + 1; }
        if (p2 > av)      { bv = av; bi = ai; av = p2; ai = 4 * er + 2; }
        else if (p2 > bv) { bv = p2; bi = 4 * er + 2; }
        if (p3 > av)      { bv = av; bi = ai; av = p3; ai = 4 * er + 3; }
        else if (p3 > bv) { bv = p3; bi = 4 * er + 3; }

        // butterfly merge across the 16 er-lanes
        #pragma unroll
        for (int off = 8; off; off >>= 1) {
            double av2 = __shfl_xor(av, off); int ai2 = __shfl_xor(ai, off);
            double bv2 = __shfl_xor(bv, off); int bi2 = __shfl_xor(bi, off);
            bool aWins = (av > av2) || (av == av2 && ai < ai2);
            if (aWins) {
                bool t = (bv > av2) || (bv == av2 && bi < ai2);
                if (!t) { bv = av2; bi = ai2; }
            } else {
                bool t = (av > bv2) || (av == bv2 && ai < bi2);
                if (t) { bv = av; bi = ai; }
                else   { bv = bv2; bi = bi2; }
                av = av2; ai = ai2;
            }
        }
        if (er == 0) {
            int tok = tok0 + tb + i;
            gate[tok] = av;
            e1a[tok] = ai;
            e2a[tok] = bi;
            p1a[tok] = (float)av;
            p2a[tok] = (float)bv;
        }
    }

    // block-level stats reduction (reuse smem, all waves past last barrier)
    double* sp_sm = smem_d;          // [16][64]
    double* z_sm  = smem_d + 16 * 64;
    const int r = wave * 4 + tr;
    #pragma unroll
    for (int j = 0; j < 4; ++j) sp_sm[r * 64 + 4 * er + j] = sp[j];
    if (er == 0) z_sm[r] = zpart;
    __syncthreads();
    if (wave == 0) {
        double v = 0.0;
        #pragma unroll
        for (int r2 = 0; r2 < 16; ++r2) v += sp_sm[r2 * 64 + lane];
        atomicAdd(&sumP[g * En + lane], v);
        if (lane == 0) {
            double zz = 0.0;
            #pragma unroll
            for (int r2 = 0; r2 < 16; ++r2) zz += z_sm[r2];
            atomicAdd(zsum, zz);
        }
    }
}

// ---------------------------------------------------------------------------
// Kernel 2: blocks 0..3 = per-group bitonic sort of 4096 tokens by
// (gate desc, idx asc) + fused gather (eseq/tseq emitted straight from LDS);
// blocks 4..259 = zero-fill the remaining 256 MB of the output.
// ---------------------------------------------------------------------------
__global__ __launch_bounds__(1024) void k_sortfill(
    const double* __restrict__ gate,
    const int* __restrict__ e1a, const int* __restrict__ e2a,
    int* __restrict__ eseq, int* __restrict__ tseq,
    float4* __restrict__ outz)
{
    __shared__ double key[4096];
    __shared__ int    val[4096];

    if (blockIdx.x >= 4) {
        // zero-fill: 65536 float4 per block, offset past gemmfill's 768 MB
        float4* dst = outz + (size_t)768 * 65536 + (size_t)(blockIdx.x - 4) * 65536;
        const float4 z4 = make_float4(0.f, 0.f, 0.f, 0.f);
        #pragma unroll 8
        for (int u = 0; u < 64; ++u) dst[threadIdx.x + 1024 * u] = z4;
        return;
    }

    const int g = blockIdx.x;
    for (int i = threadIdx.x; i < Tn; i += 1024) {
        key[i] = gate[g * Tn + i];
        val[i] = i;
    }
    __syncthreads();
    for (int k = 2; k <= Tn; k <<= 1) {
        for (int j = k >> 1; j > 0; j >>= 1) {
            for (int i = threadIdx.x; i < Tn; i += 1024) {
                int ixj = i ^ j;
                if (ixj > i) {
                    bool dir = ((i & k) == 0);
                    double ka = key[i], kb = key[ixj];
                    int    va = val[i], vb = val[ixj];
                    bool bFirst = (kb > ka) || (kb == ka && vb < va);
                    if (bFirst == dir) {
                        key[i] = kb; key[ixj] = ka;
                        val[i] = vb; val[ixj] = va;
                    }
                }
            }
            __syncthreads();
        }
    }
    // fused gather: sorted token ids are in val[]; emit cumsum-order sequences
    for (int i = threadIdx.x; i < Tn; i += 1024) {
        int tok = val[i];
        int b = g * 2 * Tn;
        tseq[b + i]      = tok;
        tseq[b + Tn + i] = tok;
        eseq[b + i]      = e1a[g * Tn + tok];
        eseq[b + Tn + i] = e2a[g * Tn + tok];
    }
}

// ---------------------------------------------------------------------------
// Kernel 3: sequential capacity assignment. One wave per group.
// ---------------------------------------------------------------------------
__global__ __launch_bounds__(64) void k_prio(
    const int* __restrict__ eseq, const int* __restrict__ tseq,
    int* __restrict__ pr1, int* __restrict__ pr2, int* __restrict__ cnt)
{
    const int g = blockIdx.x;
    const int lane = threadIdx.x;
    int base = 0;   // running count for expert == lane

    for (int c = 0; c < 2 * Tn / 64; ++c) {
        int j   = c * 64 + lane;
        int e   = eseq[g * 2 * Tn + j];
        int tok = tseq[g * 2 * Tn + j];

        unsigned long long m  = ~0ull;
        unsigned long long mo = ~0ull;
        #pragma unroll
        for (int bb = 0; bb < 6; ++bb) {
            unsigned long long bal = __ballot((e >> bb) & 1);
            m  &= ((e    >> bb) & 1) ? bal : ~bal;
            mo &= ((lane >> bb) & 1) ? bal : ~bal;
        }
        int rank   = __popcll(m & ((1ull << lane) - 1ull));
        int myBase = __shfl(base, e);
        int pr     = myBase + rank;
        if (j < Tn) pr1[g * Tn + tok] = pr;
        else        pr2[g * Tn + tok] = pr;
        base += __popcll(mo);
    }
    cnt[g * En + lane] = base;
}

// ---------------------------------------------------------------------------
// Kernel 4: blocks 0..63 scatter the <=2 nonzeros per token into
// dispatch & combine; block 64 finalizes aux_loss and z_loss.
// ---------------------------------------------------------------------------
__global__ __launch_bounds__(256) void k_scatfin(
    const int* __restrict__ e1a, const int* __restrict__ e2a,
    const float* __restrict__ p1a, const float* __restrict__ p2a,
    const int* __restrict__ pr1, const int* __restrict__ pr2,
    const int* __restrict__ cnt, const double* __restrict__ sumP,
    const double* __restrict__ zsum, float* __restrict__ out)
{
    if (blockIdx.x == 64) {
        __shared__ double red[256];
        int t = threadIdx.x;
        red[t] = (double)cnt[t] * sumP[t];
        __syncthreads();
        for (int s = 128; s; s >>= 1) {
            if (t < s) red[t] += red[t + s];
            __syncthreads();
        }
        if (t == 0) {
            double aux = red[0] * ((double)En / ((double)Gn * (double)Tn * (double)Tn));
            out[2 * NDC]     = (float)aux;
            out[2 * NDC + 1] = (float)(zsum[0] / ((double)Gn * Tn * En));
        }
        return;
    }

    int tok = blockIdx.x * 256 + threadIdx.x;
    size_t base = (size_t)tok * En * Cn;
    int p = pr1[tok];
    if (p < Cn) {
        size_t o = base + (size_t)e1a[tok] * Cn + p;
        out[o] = 1.0f;
        out[NDC + o] = p1a[tok];
    }
    p = pr2[tok];
    if (p < Cn) {
        size_t o = base + (size_t)e2a[tok] * Cn + p;
        out[o] = 1.0f;
        out[NDC + o] = p2a[tok];
    }
}

// ---------------------------------------------------------------------------
extern "C" void kernel_launch(void* const* d_in, const int* in_sizes, int n_in,
                              void* d_out, int out_size, void* d_ws, size_t ws_size,
                              hipStream_t stream)
{
    const float* x    = (const float*)d_in[0];   // [G,T,D] fp32
    const float* Wm   = (const float*)d_in[1];   // [D,E] fp32
    const float* bias = (const float*)d_in[2];   // [E] fp32
    float* out = (float*)d_out;

    // workspace carve (8-byte aligned in declaration order)
    double* gate = (double*)d_ws;            // NT doubles
    double* sumP = gate + NT;                // G*E doubles
    double* zsum = sumP + Gn * En;           // 1 double
    int* e1a  = (int*)(zsum + 1);            // NT
    int* e2a  = e1a + NT;                    // NT
    int* pr1  = e2a + NT;                    // NT
    int* pr2  = pr1 + NT;                    // NT
    int* cnt  = pr2 + NT;                    // G*E
    int* eseq = cnt + Gn * En;               // G*2T
    int* tseq = eseq + Gn * 2 * Tn;          // G*2T
    float* p1a = (float*)(tseq + Gn * 2 * Tn);
    float* p2a = p1a + NT;

    // zero the fp64 accumulators (sumP[256] + zsum[1], contiguous)
    hipMemsetAsync(sumP, 0, (Gn * En + 1) * sizeof(double), stream);

    // GEMM (256 blocks) + 768 MB of the output zero-fill (768 blocks)
    k_gemmfill<<<1024, 256, 0, stream>>>(x, Wm, bias, gate, e1a, e2a, p1a, p2a,
                                         sumP, zsum, (float4*)out);

    // sort+gather (4 blocks) + remaining 256 MB zero-fill (256 blocks)
    k_sortfill<<<260, 1024, 0, stream>>>(gate, e1a, e2a, eseq, tseq, (float4*)out);

    k_prio<<<Gn, 64, 0, stream>>>(eseq, tseq, pr1, pr2, cnt);
    k_scatfin<<<65, 256, 0, stream>>>(e1a, e2a, p1a, p2a, pr1, pr2,
                                      cnt, sumP, zsum, out);
}

// Round 6
// 1363.535 us; speedup vs baseline: 1.0173x; 1.0134x over previous
//
#include <hip/hip_runtime.h>

// Problem constants (Switch-Transformer tokens-choose router)
constexpr int Gn = 4;      // groups
constexpr int Tn = 4096;   // tokens per group
constexpr int Dn = 2048;   // d_model
constexpr int En = 64;     // experts
constexpr int Cn = 128;    // expert capacity
constexpr int NT = Gn * Tn;                  // 16384 tokens total
constexpr size_t NDC = (size_t)NT * En * Cn; // 134217728 elements per [g,t,e,c]

// Output fill plan: 1024 x 1 MB blocks total, split across the three phases
// so HBM writes always overlap otherwise-idle compute: gemm hides 640 MB,
// sort hides 256 MB, prio hides 128 MB.
constexpr int FILL_GEMM = 640;
constexpr int FILL_SORT = 256;
constexpr int FILL_PRIO = 128;

// ---------------------------------------------------------------------------
// Kernel 1: blocks 0..255 = fp64 router GEMM + softmax + top-2 + stats;
//           blocks 256..895 = zero-fill 1 MB each (first 640 MB of output).
// GEMM block: 64 tokens x 64 experts, K-tiles of 64, per-lane 4x4 fp64 acc.
// LDS fp32 tiles row-major along k: xs[64 tok][68], ws[64 k][64 e]; all
// staging/compute LDS ops are b128. Stats: per-block private slots (no
// atomics, no pre-zeroing needed).
// ---------------------------------------------------------------------------
__global__ __launch_bounds__(256) void k_gemmfill(
    const float* __restrict__ x, const float* __restrict__ Wm,
    const float* __restrict__ bias,
    double* __restrict__ gate, int* __restrict__ e1a, int* __restrict__ e2a,
    float* __restrict__ p1a, float* __restrict__ p2a,
    double* __restrict__ spartG, double* __restrict__ zpartArr,
    float4* __restrict__ outz)
{
    __shared__ double smem_d[4224];              // 33792 B, reused for stats

    if (blockIdx.x >= 256) {
        // ---- zero-fill path: 65536 float4 (1 MB) per block ----
        float4* dst = outz + (size_t)(blockIdx.x - 256) * 65536;
        const float4 z4 = make_float4(0.f, 0.f, 0.f, 0.f);
        #pragma unroll 8
        for (int u = 0; u < 256; ++u) dst[threadIdx.x + 256 * u] = z4;
        return;
    }

    float* xs = (float*)smem_d;                  // [64][68] fp32, row = token
    float* ws = (float*)smem_d + 64 * 68;        // [64][64] fp32, row = k

    const int tid  = threadIdx.x;
    const int lane = tid & 63;
    const int wave = tid >> 6;
    const int er   = lane & 15;      // expert quad: experts 4er..4er+3
    const int tr   = lane >> 4;      // token quad within wave
    const int tok0 = blockIdx.x * 64;

    // staging mapping: kq = k-float4 within tile, tg = token group
    const int kq = tid & 15;
    const int tg = tid >> 4;

    double acc[4][4];
    #pragma unroll
    for (int i = 0; i < 4; ++i)
        #pragma unroll
        for (int j = 0; j < 4; ++j) acc[i][j] = 0.0;

    float4 px[4], pw[4];
    // prefetch tile 0
    #pragma unroll
    for (int j = 0; j < 4; ++j)
        px[j] = *(const float4*)(x + (size_t)(tok0 + tg * 4 + j) * Dn + 4 * kq);
    #pragma unroll
    for (int j = 0; j < 4; ++j)
        pw[j] = ((const float4*)Wm)[tid + 256 * j];

    const int tb = wave * 16 + tr * 4;   // token base for this lane
    const float* xsp = xs + tb * 68;
    const float* wsp = ws + 4 * er;

    for (int it = 0; it < 32; ++it) {
        // commit prefetched regs to LDS — all b128 writes
        #pragma unroll
        for (int j = 0; j < 4; ++j)
            *(float4*)(xs + (tg * 4 + j) * 68 + 4 * kq) = px[j];
        #pragma unroll
        for (int j = 0; j < 4; ++j)
            ((float4*)ws)[tid + 256 * j] = pw[j];
        __syncthreads();

        // prefetch next tile (completes during compute below)
        if (it < 31) {
            const int k0 = (it + 1) * 64;
            #pragma unroll
            for (int j = 0; j < 4; ++j)
                px[j] = *(const float4*)(x + (size_t)(tok0 + tg * 4 + j) * Dn + k0 + 4 * kq);
            #pragma unroll
            for (int j = 0; j < 4; ++j)
                pw[j] = ((const float4*)(Wm + (size_t)k0 * En))[tid + 256 * j];
        }

        // compute: 16 k4-steps; each = 8 b128 reads + 64 fp64 FMAs
        #pragma unroll 2
        for (int kk = 0; kk < 16; ++kk) {
            float4 xq0 = *(const float4*)(xsp + 0 * 68 + 4 * kk);
            float4 xq1 = *(const float4*)(xsp + 1 * 68 + 4 * kk);
            float4 xq2 = *(const float4*)(xsp + 2 * 68 + 4 * kk);
            float4 xq3 = *(const float4*)(xsp + 3 * 68 + 4 * kk);
            #pragma unroll
            for (int j = 0; j < 4; ++j) {
                float4 wf = *(const float4*)(wsp + (4 * kk + j) * 64);
                double w0 = (double)wf.x, w1 = (double)wf.y;
                double w2 = (double)wf.z, w3 = (double)wf.w;
                double xv0 = (double)((const float*)&xq0)[j];
                double xv1 = (double)((const float*)&xq1)[j];
                double xv2 = (double)((const float*)&xq2)[j];
                double xv3 = (double)((const float*)&xq3)[j];
                acc[0][0] += xv0 * w0; acc[0][1] += xv0 * w1;
                acc[0][2] += xv0 * w2; acc[0][3] += xv0 * w3;
                acc[1][0] += xv1 * w0; acc[1][1] += xv1 * w1;
                acc[1][2] += xv1 * w2; acc[1][3] += xv1 * w3;
                acc[2][0] += xv2 * w0; acc[2][1] += xv2 * w1;
                acc[2][2] += xv2 * w2; acc[2][3] += xv2 * w3;
                acc[3][0] += xv3 * w0; acc[3][1] += xv3 * w1;
                acc[3][2] += xv3 * w2; acc[3][3] += xv3 * w3;
            }
        }
        __syncthreads();
    }

    // ---------------- epilogue: softmax + top-2 + stats ----------------
    const double b0 = (double)bias[4 * er + 0];
    const double b1 = (double)bias[4 * er + 1];
    const double b2 = (double)bias[4 * er + 2];
    const double b3 = (double)bias[4 * er + 3];
    double sp[4] = {0.0, 0.0, 0.0, 0.0};
    double zpart = 0.0;

    #pragma unroll
    for (int i = 0; i < 4; ++i) {
        double l0 = acc[i][0] + b0, l1 = acc[i][1] + b1;
        double l2 = acc[i][2] + b2, l3 = acc[i][3] + b3;
        double m = fmax(fmax(l0, l1), fmax(l2, l3));
        #pragma unroll
        for (int off = 8; off; off >>= 1) m = fmax(m, __shfl_xor(m, off));
        double e0v = exp(l0 - m), e1v = exp(l1 - m);
        double e2v = exp(l2 - m), e3v = exp(l3 - m);
        double s = e0v + e1v + e2v + e3v;
        #pragma unroll
        for (int off = 8; off; off >>= 1) s += __shfl_xor(s, off);
        double inv = 1.0 / s;
        double p0 = e0v * inv, p1 = e1v * inv, p2 = e2v * inv, p3 = e3v * inv;
        sp[0] += p0; sp[1] += p1; sp[2] += p2; sp[3] += p3;
        double lse = m + log(s);
        double z = (l0 - lse) * (l0 - lse) + (l1 - lse) * (l1 - lse)
                 + (l2 - lse) * (l2 - lse) + (l3 - lse) * (l3 - lse);
        #pragma unroll
        for (int off = 8; off; off >>= 1) z += __shfl_xor(z, off);
        zpart += z;

        // local top-2 over the 4 owned experts (ties -> lower index)
        double av, bv; int ai, bi;
        if (p1 > p0) { av = p1; ai = 4 * er + 1; bv = p0; bi = 4 * er; }
        else         { av = p0; ai = 4 * er;     bv = p1; bi = 4 * er + 1; }
        if (p2 > av)      { bv = av; bi = ai; av = p2; ai = 4 * er + 2; }
        else if (p2 > bv) { bv = p2; bi = 4 * er + 2; }
        if (p3 > av)      { bv = av; bi = ai; av = p3; ai = 4 * er + 3; }
        else if (p3 > bv) { bv = p3; bi = 4 * er + 3; }

        // butterfly merge across the 16 er-lanes
        #pragma unroll
        for (int off = 8; off; off >>= 1) {
            double av2 = __shfl_xor(av, off); int ai2 = __shfl_xor(ai, off);
            double bv2 = __shfl_xor(bv, off); int bi2 = __shfl_xor(bi, off);
            bool aWins = (av > av2) || (av == av2 && ai < ai2);
            if (aWins) {
                bool t = (bv > av2) || (bv == av2 && bi < ai2);
                if (!t) { bv = av2; bi = ai2; }
            } else {
                bool t = (av > bv2) || (av == bv2 && ai < bi2);
                if (t) { bv = av; bi = ai; }
                else   { bv = bv2; bi = bi2; }
                av = av2; ai = ai2;
            }
        }
        if (er == 0) {
            int tok = tok0 + tb + i;
            gate[tok] = av;
            e1a[tok] = ai;
            e2a[tok] = bi;
            p1a[tok] = (float)av;
            p2a[tok] = (float)bv;
        }
    }

    // block-level stats reduction -> private per-block slots (no atomics)
    double* sp_sm = smem_d;          // [16][64]
    double* z_sm  = smem_d + 16 * 64;
    const int r = wave * 4 + tr;
    #pragma unroll
    for (int j = 0; j < 4; ++j) sp_sm[r * 64 + 4 * er + j] = sp[j];
    if (er == 0) z_sm[r] = zpart;
    __syncthreads();
    if (wave == 0) {
        double v = 0.0;
        #pragma unroll
        for (int r2 = 0; r2 < 16; ++r2) v += sp_sm[r2 * 64 + lane];
        spartG[blockIdx.x * 64 + lane] = v;
        if (lane == 0) {
            double zz = 0.0;
            #pragma unroll
            for (int r2 = 0; r2 < 16; ++r2) zz += z_sm[r2];
            zpartArr[blockIdx.x] = zz;
        }
    }
}

// ---------------------------------------------------------------------------
// Kernel 2: blocks 0..3 = per-group bitonic sort of 4096 tokens by
// (gate desc, idx asc) + fused gather; blocks 4..259 = zero-fill 256 MB.
// ---------------------------------------------------------------------------
__global__ __launch_bounds__(1024) void k_sortfill(
    const double* __restrict__ gate,
    const int* __restrict__ e1a, const int* __restrict__ e2a,
    int* __restrict__ eseq, int* __restrict__ tseq,
    float4* __restrict__ outz)
{
    __shared__ double key[4096];
    __shared__ int    val[4096];

    if (blockIdx.x >= 4) {
        float4* dst = outz + (size_t)FILL_GEMM * 65536
                           + (size_t)(blockIdx.x - 4) * 65536;
        const float4 z4 = make_float4(0.f, 0.f, 0.f, 0.f);
        #pragma unroll 8
        for (int u = 0; u < 64; ++u) dst[threadIdx.x + 1024 * u] = z4;
        return;
    }

    const int g = blockIdx.x;
    for (int i = threadIdx.x; i < Tn; i += 1024) {
        key[i] = gate[g * Tn + i];
        val[i] = i;
    }
    __syncthreads();
    for (int k = 2; k <= Tn; k <<= 1) {
        for (int j = k >> 1; j > 0; j >>= 1) {
            for (int i = threadIdx.x; i < Tn; i += 1024) {
                int ixj = i ^ j;
                if (ixj > i) {
                    bool dir = ((i & k) == 0);
                    double ka = key[i], kb = key[ixj];
                    int    va = val[i], vb = val[ixj];
                    bool bFirst = (kb > ka) || (kb == ka && vb < va);
                    if (bFirst == dir) {
                        key[i] = kb; key[ixj] = ka;
                        val[i] = vb; val[ixj] = va;
                    }
                }
            }
            __syncthreads();
        }
    }
    // fused gather: emit cumsum-order sequences straight from sorted LDS
    for (int i = threadIdx.x; i < Tn; i += 1024) {
        int tok = val[i];
        int b = g * 2 * Tn;
        tseq[b + i]      = tok;
        tseq[b + Tn + i] = tok;
        eseq[b + i]      = e1a[g * Tn + tok];
        eseq[b + Tn + i] = e2a[g * Tn + tok];
    }
}

// ---------------------------------------------------------------------------
// Kernel 3: blocks 0..3 = sequential capacity assignment (one wave each,
// next-chunk loads prefetched ahead of the ballot chain);
// blocks 4..131 = zero-fill the last 128 MB of the output.
// ---------------------------------------------------------------------------
__global__ __launch_bounds__(256) void k_priofill(
    const int* __restrict__ eseq, const int* __restrict__ tseq,
    int* __restrict__ pr1, int* __restrict__ pr2, int* __restrict__ cnt,
    float4* __restrict__ outz)
{
    if (blockIdx.x >= 4) {
        float4* dst = outz + (size_t)(FILL_GEMM + FILL_SORT) * 65536
                           + (size_t)(blockIdx.x - 4) * 65536;
        const float4 z4 = make_float4(0.f, 0.f, 0.f, 0.f);
        #pragma unroll 8
        for (int u = 0; u < 256; ++u) dst[threadIdx.x + 256 * u] = z4;
        return;
    }
    if (threadIdx.x >= 64) return;

    const int g = blockIdx.x;
    const int lane = threadIdx.x;
    const int gb = g * 2 * Tn;
    int base = 0;   // running count for expert == lane

    int e   = eseq[gb + lane];
    int tok = tseq[gb + lane];

    for (int c = 0; c < 2 * Tn / 64; ++c) {
        // prefetch next chunk before the dependent ballot chain
        int en = 0, tn2 = 0;
        if (c < 2 * Tn / 64 - 1) {
            en  = eseq[gb + (c + 1) * 64 + lane];
            tn2 = tseq[gb + (c + 1) * 64 + lane];
        }

        unsigned long long m  = ~0ull;   // entries matching MY entry's expert
        unsigned long long mo = ~0ull;   // entries matching my owned expert
        #pragma unroll
        for (int bb = 0; bb < 6; ++bb) {
            unsigned long long bal = __ballot((e >> bb) & 1);
            m  &= ((e    >> bb) & 1) ? bal : ~bal;
            mo &= ((lane >> bb) & 1) ? bal : ~bal;
        }
        int rank   = __popcll(m & ((1ull << lane) - 1ull));
        int myBase = __shfl(base, e);
        int pr     = myBase + rank;
        int j      = c * 64 + lane;
        if (j < Tn) pr1[g * Tn + tok] = pr;
        else        pr2[g * Tn + tok] = pr;
        base += __popcll(mo);

        e = en; tok = tn2;
    }
    cnt[g * En + lane] = base;
}

// ---------------------------------------------------------------------------
// Kernel 4: blocks 0..63 scatter the <=2 nonzeros per token into
// dispatch & combine; block 64 reduces stat partials -> aux_loss, z_loss.
// ---------------------------------------------------------------------------
__global__ __launch_bounds__(256) void k_scatfin(
    const int* __restrict__ e1a, const int* __restrict__ e2a,
    const float* __restrict__ p1a, const float* __restrict__ p2a,
    const int* __restrict__ pr1, const int* __restrict__ pr2,
    const int* __restrict__ cnt, const double* __restrict__ spartG,
    const double* __restrict__ zpartArr, float* __restrict__ out)
{
    if (blockIdx.x == 64) {
        __shared__ double red[256];
        __shared__ double zred[256];
        int t = threadIdx.x;            // t = g*64 + e
        int g = t >> 6, e = t & 63;
        double s = 0.0;
        #pragma unroll 8
        for (int lb = 0; lb < 64; ++lb)
            s += spartG[((g << 6) + lb) * 64 + e];
        red[t]  = (double)cnt[t] * s;
        zred[t] = zpartArr[t];
        __syncthreads();
        for (int st = 128; st; st >>= 1) {
            if (t < st) { red[t] += red[t + st]; zred[t] += zred[t + st]; }
            __syncthreads();
        }
        if (t == 0) {
            double aux = red[0] * ((double)En / ((double)Gn * (double)Tn * (double)Tn));
            out[2 * NDC]     = (float)aux;
            out[2 * NDC + 1] = (float)(zred[0] / ((double)Gn * Tn * En));
        }
        return;
    }

    int tok = blockIdx.x * 256 + threadIdx.x;
    size_t base = (size_t)tok * En * Cn;
    int p = pr1[tok];
    if (p < Cn) {
        size_t o = base + (size_t)e1a[tok] * Cn + p;
        out[o] = 1.0f;
        out[NDC + o] = p1a[tok];
    }
    p = pr2[tok];
    if (p < Cn) {
        size_t o = base + (size_t)e2a[tok] * Cn + p;
        out[o] = 1.0f;
        out[NDC + o] = p2a[tok];
    }
}

// ---------------------------------------------------------------------------
extern "C" void kernel_launch(void* const* d_in, const int* in_sizes, int n_in,
                              void* d_out, int out_size, void* d_ws, size_t ws_size,
                              hipStream_t stream)
{
    const float* x    = (const float*)d_in[0];   // [G,T,D] fp32
    const float* Wm   = (const float*)d_in[1];   // [D,E] fp32
    const float* bias = (const float*)d_in[2];   // [E] fp32
    float* out = (float*)d_out;

    // workspace carve (8-byte aligned in declaration order)
    double* gate     = (double*)d_ws;            // NT doubles
    double* spartG   = gate + NT;                // 256*64 doubles
    double* zpartArr = spartG + 256 * 64;        // 256 doubles
    int* e1a  = (int*)(zpartArr + 256);          // NT
    int* e2a  = e1a + NT;                        // NT
    int* pr1  = e2a + NT;                        // NT
    int* pr2  = pr1 + NT;                        // NT
    int* cnt  = pr2 + NT;                        // G*E
    int* eseq = cnt + Gn * En;                   // G*2T
    int* tseq = eseq + Gn * 2 * Tn;              // G*2T
    float* p1a = (float*)(tseq + Gn * 2 * Tn);
    float* p2a = p1a + NT;

    // GEMM (256 blocks) + first 640 MB of the output zero-fill
    k_gemmfill<<<256 + FILL_GEMM, 256, 0, stream>>>(
        x, Wm, bias, gate, e1a, e2a, p1a, p2a, spartG, zpartArr, (float4*)out);

    // sort+gather (4 blocks) + next 256 MB zero-fill
    k_sortfill<<<4 + FILL_SORT, 1024, 0, stream>>>(
        gate, e1a, e2a, eseq, tseq, (float4*)out);

    // capacity assignment (4 blocks) + last 128 MB zero-fill
    k_priofill<<<4 + FILL_PRIO, 256, 0, stream>>>(
        eseq, tseq, pr1, pr2, cnt, (float4*)out);

    k_scatfin<<<65, 256, 0, stream>>>(e1a, e2a, p1a, p2a, pr1, pr2,
                                      cnt, spartG, zpartArr, out);
}

// Round 7
// 1290.326 us; speedup vs baseline: 1.0750x; 1.0567x over previous
//
#include <hip/hip_runtime.h>

// Problem constants (Switch-Transformer tokens-choose router)
constexpr int Gn = 4;      // groups
constexpr int Tn = 4096;   // tokens per group
constexpr int Dn = 2048;   // d_model
constexpr int En = 64;     // experts
constexpr int Cn = 128;    // expert capacity
constexpr int NT = Gn * Tn;                  // 16384 tokens total
constexpr size_t NDC = (size_t)NT * En * Cn; // 134217728 elements per [g,t,e,c]

// Output zero-fill plan (1 MB units, 1024 total), spread so HBM writes
// overlap otherwise-idle compute in every phase.
constexpr int FILL_GEMM = 384;   // [0, 384) MB
constexpr int FILL_EPI  = 64;    // [384, 448)
constexpr int FILL_SORT = 448;   // [448, 896)
constexpr int FILL_PRIO = 128;   // [896, 1024)

// ---------------------------------------------------------------------------
// Kernel 1: blocks 0..511 = split-K fp64 router GEMM. Block b: tile t=b>>1
// (64 tokens), K-half h=b&1 (K=1024, 16 K-tiles of 64). Per-lane 4x4 fp64
// acc -> fp64 partial [64][64] written to ws. 512 blocks = 2/CU = 2 waves/SIMD
// so FMA/cvt/LDS pipes overlap across waves (1 wave/SIMD was latency-exposed).
// Blocks 512..895 zero-fill 1 MB each of the output.
// ---------------------------------------------------------------------------
__global__ __launch_bounds__(256) void k_gemm(
    const float* __restrict__ x, const float* __restrict__ Wm,
    double* __restrict__ part, float4* __restrict__ outz)
{
    __shared__ float smem[64 * 68 + 64 * 64];    // xs | ws tiles, 33792 B

    if (blockIdx.x >= 512) {
        float4* dst = outz + (size_t)(blockIdx.x - 512) * 65536;
        const float4 z4 = make_float4(0.f, 0.f, 0.f, 0.f);
        #pragma unroll 8
        for (int u = 0; u < 256; ++u) dst[threadIdx.x + 256 * u] = z4;
        return;
    }

    float* xs = smem;                  // [64][68] fp32, row = token
    float* ws = smem + 64 * 68;        // [64][64] fp32, row = k

    const int tid  = threadIdx.x;
    const int lane = tid & 63;
    const int wave = tid >> 6;
    const int er   = lane & 15;      // expert quad: experts 4er..4er+3
    const int tr   = lane >> 4;      // token quad within wave
    const int t    = blockIdx.x >> 1;
    const int h    = blockIdx.x & 1;
    const int tok0 = t * 64;
    const int kbase = h * 1024;

    const int kq = tid & 15;         // k-float4 within tile
    const int tg = tid >> 4;         // token group for staging

    double acc[4][4];
    #pragma unroll
    for (int i = 0; i < 4; ++i)
        #pragma unroll
        for (int j = 0; j < 4; ++j) acc[i][j] = 0.0;

    float4 px[4], pw[4];
    #pragma unroll
    for (int j = 0; j < 4; ++j)
        px[j] = *(const float4*)(x + (size_t)(tok0 + tg * 4 + j) * Dn + kbase + 4 * kq);
    #pragma unroll
    for (int j = 0; j < 4; ++j)
        pw[j] = ((const float4*)(Wm + (size_t)kbase * En))[tid + 256 * j];

    const int tb = wave * 16 + tr * 4;   // token base for this lane
    const float* xsp = xs + tb * 68;
    const float* wsp = ws + 4 * er;

    for (int it = 0; it < 16; ++it) {
        #pragma unroll
        for (int j = 0; j < 4; ++j)
            *(float4*)(xs + (tg * 4 + j) * 68 + 4 * kq) = px[j];
        #pragma unroll
        for (int j = 0; j < 4; ++j)
            ((float4*)ws)[tid + 256 * j] = pw[j];
        __syncthreads();

        if (it < 15) {
            const int k0 = kbase + (it + 1) * 64;
            #pragma unroll
            for (int j = 0; j < 4; ++j)
                px[j] = *(const float4*)(x + (size_t)(tok0 + tg * 4 + j) * Dn + k0 + 4 * kq);
            #pragma unroll
            for (int j = 0; j < 4; ++j)
                pw[j] = ((const float4*)(Wm + (size_t)k0 * En))[tid + 256 * j];
        }

        #pragma unroll 2
        for (int kk = 0; kk < 16; ++kk) {
            float4 xq0 = *(const float4*)(xsp + 0 * 68 + 4 * kk);
            float4 xq1 = *(const float4*)(xsp + 1 * 68 + 4 * kk);
            float4 xq2 = *(const float4*)(xsp + 2 * 68 + 4 * kk);
            float4 xq3 = *(const float4*)(xsp + 3 * 68 + 4 * kk);
            #pragma unroll
            for (int j = 0; j < 4; ++j) {
                float4 wf = *(const float4*)(wsp + (4 * kk + j) * 64);
                double w0 = (double)wf.x, w1 = (double)wf.y;
                double w2 = (double)wf.z, w3 = (double)wf.w;
                double xv0 = (double)((const float*)&xq0)[j];
                double xv1 = (double)((const float*)&xq1)[j];
                double xv2 = (double)((const float*)&xq2)[j];
                double xv3 = (double)((const float*)&xq3)[j];
                acc[0][0] += xv0 * w0; acc[0][1] += xv0 * w1;
                acc[0][2] += xv0 * w2; acc[0][3] += xv0 * w3;
                acc[1][0] += xv1 * w0; acc[1][1] += xv1 * w1;
                acc[1][2] += xv1 * w2; acc[1][3] += xv1 * w3;
                acc[2][0] += xv2 * w0; acc[2][1] += xv2 * w1;
                acc[2][2] += xv2 * w2; acc[2][3] += xv2 * w3;
                acc[3][0] += xv3 * w0; acc[3][1] += xv3 * w1;
                acc[3][2] += xv3 * w2; acc[3][3] += xv3 * w3;
            }
        }
        __syncthreads();
    }

    // store fp64 partial tile [64 tok][64 exp] for this K-half
    double* dst = part + (size_t)blockIdx.x * 4096;
    #pragma unroll
    for (int i = 0; i < 4; ++i) {
        *(double2*)(dst + (tb + i) * 64 + 4 * er)     = double2{acc[i][0], acc[i][1]};
        *(double2*)(dst + (tb + i) * 64 + 4 * er + 2) = double2{acc[i][2], acc[i][3]};
    }
}

// ---------------------------------------------------------------------------
// Kernel 2: blocks 0..255 = per-tile epilogue: sum the two K-half partials,
// softmax + top-2 + stats (same lane layout as k_gemm).
// Blocks 256..319 = zero-fill 1 MB each.
// ---------------------------------------------------------------------------
__global__ __launch_bounds__(256) void k_epi(
    const double* __restrict__ part, const float* __restrict__ bias,
    double* __restrict__ gate, int* __restrict__ e1a, int* __restrict__ e2a,
    float* __restrict__ p1a, float* __restrict__ p2a,
    double* __restrict__ spartG, double* __restrict__ zpartArr,
    float4* __restrict__ outz)
{
    __shared__ double smem_d[16 * 64 + 16];

    if (blockIdx.x >= 256) {
        float4* dst = outz + (size_t)FILL_GEMM * 65536
                           + (size_t)(blockIdx.x - 256) * 65536;
        const float4 z4 = make_float4(0.f, 0.f, 0.f, 0.f);
        #pragma unroll 8
        for (int u = 0; u < 256; ++u) dst[threadIdx.x + 256 * u] = z4;
        return;
    }

    const int tid  = threadIdx.x;
    const int lane = tid & 63;
    const int wave = tid >> 6;
    const int er   = lane & 15;
    const int tr   = lane >> 4;
    const int t    = blockIdx.x;
    const int tok0 = t * 64;
    const int tb   = wave * 16 + tr * 4;

    const double* pa = part + (size_t)(2 * t) * 4096;
    const double* pb = part + (size_t)(2 * t + 1) * 4096;

    double acc[4][4];
    #pragma unroll
    for (int i = 0; i < 4; ++i) {
        int off = (tb + i) * 64 + 4 * er;
        double2 a0 = *(const double2*)(pa + off);
        double2 a1 = *(const double2*)(pa + off + 2);
        double2 c0 = *(const double2*)(pb + off);
        double2 c1 = *(const double2*)(pb + off + 2);
        acc[i][0] = a0.x + c0.x; acc[i][1] = a0.y + c0.y;
        acc[i][2] = a1.x + c1.x; acc[i][3] = a1.y + c1.y;
    }

    const double b0 = (double)bias[4 * er + 0];
    const double b1 = (double)bias[4 * er + 1];
    const double b2 = (double)bias[4 * er + 2];
    const double b3 = (double)bias[4 * er + 3];
    double sp[4] = {0.0, 0.0, 0.0, 0.0};
    double zpart = 0.0;

    #pragma unroll
    for (int i = 0; i < 4; ++i) {
        double l0 = acc[i][0] + b0, l1 = acc[i][1] + b1;
        double l2 = acc[i][2] + b2, l3 = acc[i][3] + b3;
        double m = fmax(fmax(l0, l1), fmax(l2, l3));
        #pragma unroll
        for (int off = 8; off; off >>= 1) m = fmax(m, __shfl_xor(m, off));
        double e0v = exp(l0 - m), e1v = exp(l1 - m);
        double e2v = exp(l2 - m), e3v = exp(l3 - m);
        double s = e0v + e1v + e2v + e3v;
        #pragma unroll
        for (int off = 8; off; off >>= 1) s += __shfl_xor(s, off);
        double inv = 1.0 / s;
        double p0 = e0v * inv, p1 = e1v * inv, p2 = e2v * inv, p3 = e3v * inv;
        sp[0] += p0; sp[1] += p1; sp[2] += p2; sp[3] += p3;
        double lse = m + log(s);
        double z = (l0 - lse) * (l0 - lse) + (l1 - lse) * (l1 - lse)
                 + (l2 - lse) * (l2 - lse) + (l3 - lse) * (l3 - lse);
        #pragma unroll
        for (int off = 8; off; off >>= 1) z += __shfl_xor(z, off);
        zpart += z;

        // local top-2 over the 4 owned experts (ties -> lower index)
        double av, bv; int ai, bi;
        if (p1 > p0) { av = p1; ai = 4 * er + 1; bv = p0; bi = 4 * er; }
        else         { av = p0; ai = 4 * er;     bv = p1; bi = 4 * er + 1; }
        if (p2 > av)      { bv = av; bi = ai; av = p2; ai = 4 * er + 2; }
        else if (p2 > bv) { bv = p2; bi = 4 * er + 2; }
        if (p3 > av)      { bv = av; bi = ai; av = p3; ai = 4 * er + 3; }
        else if (p3 > bv) { bv = p3; bi = 4 * er + 3; }

        // butterfly merge across the 16 er-lanes
        #pragma unroll
        for (int off = 8; off; off >>= 1) {
            double av2 = __shfl_xor(av, off); int ai2 = __shfl_xor(ai, off);
            double bv2 = __shfl_xor(bv, off); int bi2 = __shfl_xor(bi, off);
            bool aWins = (av > av2) || (av == av2 && ai < ai2);
            if (aWins) {
                bool tt = (bv > av2) || (bv == av2 && bi < ai2);
                if (!tt) { bv = av2; bi = ai2; }
            } else {
                bool tt = (av > bv2) || (av == bv2 && ai < bi2);
                if (tt) { bv = av; bi = ai; }
                else    { bv = bv2; bi = bi2; }
                av = av2; ai = ai2;
            }
        }
        if (er == 0) {
            int tok = tok0 + tb + i;
            gate[tok] = av;
            e1a[tok] = ai;
            e2a[tok] = bi;
            p1a[tok] = (float)av;
            p2a[tok] = (float)bv;
        }
    }

    // per-tile stats -> private slots (no atomics)
    double* sp_sm = smem_d;
    double* z_sm  = smem_d + 16 * 64;
    const int r = wave * 4 + tr;
    #pragma unroll
    for (int j = 0; j < 4; ++j) sp_sm[r * 64 + 4 * er + j] = sp[j];
    if (er == 0) z_sm[r] = zpart;
    __syncthreads();
    if (wave == 0) {
        double v = 0.0;
        #pragma unroll
        for (int r2 = 0; r2 < 16; ++r2) v += sp_sm[r2 * 64 + lane];
        spartG[t * 64 + lane] = v;
        if (lane == 0) {
            double zz = 0.0;
            #pragma unroll
            for (int r2 = 0; r2 < 16; ++r2) zz += z_sm[r2];
            zpartArr[t] = zz;
        }
    }
}

// ---------------------------------------------------------------------------
// Kernel 3: blocks 0..3 = per-group bitonic sort of 4096 tokens by
// (gate desc, idx asc) + fused gather; blocks 4.. = zero-fill.
// ---------------------------------------------------------------------------
__global__ __launch_bounds__(1024) void k_sortfill(
    const double* __restrict__ gate,
    const int* __restrict__ e1a, const int* __restrict__ e2a,
    int* __restrict__ eseq, int* __restrict__ tseq,
    float4* __restrict__ outz)
{
    __shared__ double key[4096];
    __shared__ int    val[4096];

    if (blockIdx.x >= 4) {
        float4* dst = outz + (size_t)(FILL_GEMM + FILL_EPI) * 65536
                           + (size_t)(blockIdx.x - 4) * 65536;
        const float4 z4 = make_float4(0.f, 0.f, 0.f, 0.f);
        #pragma unroll 8
        for (int u = 0; u < 64; ++u) dst[threadIdx.x + 1024 * u] = z4;
        return;
    }

    const int g = blockIdx.x;
    for (int i = threadIdx.x; i < Tn; i += 1024) {
        key[i] = gate[g * Tn + i];
        val[i] = i;
    }
    __syncthreads();
    for (int k = 2; k <= Tn; k <<= 1) {
        for (int j = k >> 1; j > 0; j >>= 1) {
            for (int i = threadIdx.x; i < Tn; i += 1024) {
                int ixj = i ^ j;
                if (ixj > i) {
                    bool dir = ((i & k) == 0);
                    double ka = key[i], kb = key[ixj];
                    int    va = val[i], vb = val[ixj];
                    bool bFirst = (kb > ka) || (kb == ka && vb < va);
                    if (bFirst == dir) {
                        key[i] = kb; key[ixj] = ka;
                        val[i] = vb; val[ixj] = va;
                    }
                }
            }
            __syncthreads();
        }
    }
    for (int i = threadIdx.x; i < Tn; i += 1024) {
        int tok = val[i];
        int b = g * 2 * Tn;
        tseq[b + i]      = tok;
        tseq[b + Tn + i] = tok;
        eseq[b + i]      = e1a[g * Tn + tok];
        eseq[b + Tn + i] = e2a[g * Tn + tok];
    }
}

// ---------------------------------------------------------------------------
// Kernel 4: blocks 0..3 = sequential capacity assignment (one wave each,
// prefetched); blocks 4.. = zero-fill the last slice of the output.
// ---------------------------------------------------------------------------
__global__ __launch_bounds__(256) void k_priofill(
    const int* __restrict__ eseq, const int* __restrict__ tseq,
    int* __restrict__ pr1, int* __restrict__ pr2, int* __restrict__ cnt,
    float4* __restrict__ outz)
{
    if (blockIdx.x >= 4) {
        float4* dst = outz + (size_t)(FILL_GEMM + FILL_EPI + FILL_SORT) * 65536
                           + (size_t)(blockIdx.x - 4) * 65536;
        const float4 z4 = make_float4(0.f, 0.f, 0.f, 0.f);
        #pragma unroll 8
        for (int u = 0; u < 256; ++u) dst[threadIdx.x + 256 * u] = z4;
        return;
    }
    if (threadIdx.x >= 64) return;

    const int g = blockIdx.x;
    const int lane = threadIdx.x;
    const int gb = g * 2 * Tn;
    int base = 0;

    int e   = eseq[gb + lane];
    int tok = tseq[gb + lane];

    for (int c = 0; c < 2 * Tn / 64; ++c) {
        int en = 0, tn2 = 0;
        if (c < 2 * Tn / 64 - 1) {
            en  = eseq[gb + (c + 1) * 64 + lane];
            tn2 = tseq[gb + (c + 1) * 64 + lane];
        }

        unsigned long long m  = ~0ull;
        unsigned long long mo = ~0ull;
        #pragma unroll
        for (int bb = 0; bb < 6; ++bb) {
            unsigned long long bal = __ballot((e >> bb) & 1);
            m  &= ((e    >> bb) & 1) ? bal : ~bal;
            mo &= ((lane >> bb) & 1) ? bal : ~bal;
        }
        int rank   = __popcll(m & ((1ull << lane) - 1ull));
        int myBase = __shfl(base, e);
        int pr     = myBase + rank;
        int j      = c * 64 + lane;
        if (j < Tn) pr1[g * Tn + tok] = pr;
        else        pr2[g * Tn + tok] = pr;
        base += __popcll(mo);

        e = en; tok = tn2;
    }
    cnt[g * En + lane] = base;
}

// ---------------------------------------------------------------------------
// Kernel 5: blocks 0..63 scatter the <=2 nonzeros per token; block 64
// reduces stat partials -> aux_loss, z_loss.
// ---------------------------------------------------------------------------
__global__ __launch_bounds__(256) void k_scatfin(
    const int* __restrict__ e1a, const int* __restrict__ e2a,
    const float* __restrict__ p1a, const float* __restrict__ p2a,
    const int* __restrict__ pr1, const int* __restrict__ pr2,
    const int* __restrict__ cnt, const double* __restrict__ spartG,
    const double* __restrict__ zpartArr, float* __restrict__ out)
{
    if (blockIdx.x == 64) {
        __shared__ double red[256];
        __shared__ double zred[256];
        int t = threadIdx.x;            // t = g*64 + e
        int g = t >> 6, e = t & 63;
        double s = 0.0;
        #pragma unroll 8
        for (int lb = 0; lb < 64; ++lb)
            s += spartG[((g << 6) + lb) * 64 + e];
        red[t]  = (double)cnt[t] * s;
        zred[t] = zpartArr[t];
        __syncthreads();
        for (int st = 128; st; st >>= 1) {
            if (t < st) { red[t] += red[t + st]; zred[t] += zred[t + st]; }
            __syncthreads();
        }
        if (t == 0) {
            double aux = red[0] * ((double)En / ((double)Gn * (double)Tn * (double)Tn));
            out[2 * NDC]     = (float)aux;
            out[2 * NDC + 1] = (float)(zred[0] / ((double)Gn * Tn * En));
        }
        return;
    }

    int tok = blockIdx.x * 256 + threadIdx.x;
    size_t base = (size_t)tok * En * Cn;
    int p = pr1[tok];
    if (p < Cn) {
        size_t o = base + (size_t)e1a[tok] * Cn + p;
        out[o] = 1.0f;
        out[NDC + o] = p1a[tok];
    }
    p = pr2[tok];
    if (p < Cn) {
        size_t o = base + (size_t)e2a[tok] * Cn + p;
        out[o] = 1.0f;
        out[NDC + o] = p2a[tok];
    }
}

// ---------------------------------------------------------------------------
extern "C" void kernel_launch(void* const* d_in, const int* in_sizes, int n_in,
                              void* d_out, int out_size, void* d_ws, size_t ws_size,
                              hipStream_t stream)
{
    const float* x    = (const float*)d_in[0];   // [G,T,D] fp32
    const float* Wm   = (const float*)d_in[1];   // [D,E] fp32
    const float* bias = (const float*)d_in[2];   // [E] fp32
    float* out = (float*)d_out;

    // workspace carve (8-byte aligned in declaration order)
    double* part     = (double*)d_ws;            // 512*4096 doubles (16.8 MB)
    double* gate     = part + (size_t)512 * 4096;
    double* spartG   = gate + NT;                // 256*64
    double* zpartArr = spartG + 256 * 64;        // 256
    int* e1a  = (int*)(zpartArr + 256);          // NT
    int* e2a  = e1a + NT;                        // NT
    int* pr1  = e2a + NT;                        // NT
    int* pr2  = pr1 + NT;                        // NT
    int* cnt  = pr2 + NT;                        // G*E
    int* eseq = cnt + Gn * En;                   // G*2T
    int* tseq = eseq + Gn * 2 * Tn;              // G*2T
    float* p1a = (float*)(tseq + Gn * 2 * Tn);
    float* p2a = p1a + NT;

    // split-K GEMM (512 blocks, 2/CU) + 384 MB zero-fill
    k_gemm<<<512 + FILL_GEMM, 256, 0, stream>>>(x, Wm, part, (float4*)out);

    // epilogue (256 blocks) + 64 MB zero-fill
    k_epi<<<256 + FILL_EPI, 256, 0, stream>>>(part, bias, gate, e1a, e2a,
                                              p1a, p2a, spartG, zpartArr,
                                              (float4*)out);

    // sort+gather (4 blocks) + 448 MB zero-fill
    k_sortfill<<<4 + FILL_SORT, 1024, 0, stream>>>(gate, e1a, e2a, eseq, tseq,
                                                   (float4*)out);

    // capacity assignment (4 blocks) + 128 MB zero-fill
    k_priofill<<<4 + FILL_PRIO, 256, 0, stream>>>(eseq, tseq, pr1, pr2, cnt,
                                                  (float4*)out);

    k_scatfin<<<65, 256, 0, stream>>>(e1a, e2a, p1a, p2a, pr1, pr2,
                                      cnt, spartG, zpartArr, out);
}